// Round 1
// 155.358 us; speedup vs baseline: 1.0442x; 1.0442x over previous
//
#include <hip/hip_runtime.h>
#include <hip/hip_bf16.h>
#include <math.h>

#define BB 8
#define NQ 1024
#define NKV 2048
#define DIM 512
#define H 8
#define DH 64
#define INNER 512
// 0.125 * log2(e): folded into Q so QK^T scores feed v_exp_f32 (2^x) directly
#define SCALE_LOG2E 0.18033688011112042f

typedef __bf16 bf16x8 __attribute__((ext_vector_type(8)));
typedef float f32x4 __attribute__((ext_vector_type(4)));
typedef unsigned int u32x4 __attribute__((ext_vector_type(4)));

__device__ __forceinline__ unsigned short f2bf(float f) {
  union { float f; unsigned int u; } v; v.f = f;
  unsigned int r = v.u + 0x7fffu + ((v.u >> 16) & 1u);
  return (unsigned short)(r >> 16);
}
__device__ __forceinline__ float bf2f(unsigned short h) {
  union { unsigned int u; float f; } v; v.u = ((unsigned int)h) << 16;
  return v.f;
}

// ---------------- K0: cast/transpose weights to bf16; Wo also hi/lo split ----------------
__global__ __launch_bounds__(256) void prep_weights(
    const float* __restrict__ Wq, const float* __restrict__ Wkv,
    const float* __restrict__ Wo,
    unsigned short* __restrict__ WqT, unsigned short* __restrict__ WkvT,
    unsigned short* __restrict__ WohT, unsigned short* __restrict__ WolT) {
  __shared__ float T[64][65];
  int blk = blockIdx.x;
  const float* src; int Wd, ti, tj, mode;
  unsigned short* dst = nullptr;
  if (blk < 64) { src = Wq;  dst = WqT;  Wd = 512;  ti = blk >> 3; tj = blk & 7; mode = 0; }
  else if (blk < 192) { int b2 = blk - 64; src = Wkv; dst = WkvT; Wd = 1024; ti = b2 >> 4; tj = b2 & 15; mode = 0; }
  else { int b2 = blk - 192; src = Wo; Wd = 512; ti = b2 >> 3; tj = b2 & 7; mode = 1; }
  int t = threadIdx.x;
#pragma unroll
  for (int i = 0; i < 16; ++i) {
    int idx = i * 256 + t;
    int r = idx >> 6, c = idx & 63;
    T[r][c] = src[(size_t)(ti * 64 + r) * Wd + tj * 64 + c];
  }
  __syncthreads();
#pragma unroll
  for (int i = 0; i < 16; ++i) {
    int idx = i * 256 + t;
    int n = idx >> 6, k = idx & 63;
    float v = T[k][n];
    size_t off = (size_t)(tj * 64 + n) * 512 + ti * 64 + k;
    if (mode == 0) {
      dst[off] = f2bf(v);
    } else {
      unsigned short hb = f2bf(v);
      WohT[off] = hb;
      WolT[off] = f2bf(v - bf2f(hb));
    }
  }
}

// ---------------- K1: LayerNorm -> bf16 ----------------
__global__ __launch_bounds__(256) void ln_kernel(
    const float* __restrict__ xq, const float* __restrict__ xc,
    const float* __restrict__ gq, const float* __restrict__ bq,
    const float* __restrict__ gc, const float* __restrict__ bc,
    unsigned short* __restrict__ xq_bf, unsigned short* __restrict__ xc_bf) {
  int row = blockIdx.x;
  const float* x; const float* g; const float* bb; unsigned short* out;
  if (row < BB * NQ) {
    x = xq + (size_t)row * DIM; g = gq; bb = bq; out = xq_bf + (size_t)row * DIM;
  } else {
    int r = row - BB * NQ;
    x = xc + (size_t)r * DIM; g = gc; bb = bc; out = xc_bf + (size_t)r * DIM;
  }
  int t = threadIdx.x;
  float2 v = *reinterpret_cast<const float2*>(x + t * 2);
  float s = v.x + v.y;
  float ss = v.x * v.x + v.y * v.y;
#pragma unroll
  for (int d = 1; d < 64; d <<= 1) { s += __shfl_xor(s, d); ss += __shfl_xor(ss, d); }
  __shared__ float red[8];
  int wid = t >> 6, lane = t & 63;
  if (lane == 0) { red[wid] = s; red[4 + wid] = ss; }
  __syncthreads();
  s = red[0] + red[1] + red[2] + red[3];
  ss = red[4] + red[5] + red[6] + red[7];
  float mu = s * (1.0f / DIM);
  float var = ss * (1.0f / DIM) - mu * mu;
  float rs = rsqrtf(var + 1e-5f);
  float y0 = (v.x - mu) * rs * g[t * 2] + bb[t * 2];
  float y1 = (v.y - mu) * rs * g[t * 2 + 1] + bb[t * 2 + 1];
  ushort2 o; o.x = f2bf(y0); o.y = f2bf(y1);
  *reinterpret_cast<ushort2*>(out + t * 2) = o;
}

// ---------------- shared MFMA GEMM mainloop: 64x64 C tile, K=512, XOR-swizzled LDS ----------------
// T14 async-STAGE: next K-step's global loads issued right after the post-stage
// barrier so HBM/L2 latency hides under the MFMA phase.
__device__ __forceinline__ void gemm_mainloop(
    const unsigned short* __restrict__ A, const unsigned short* __restrict__ WT,
    unsigned short* As, unsigned short* Ws, float (*Cs)[66],
    int rowBase, int colBase) {
  const int t = threadIdx.x;
  const int w = t >> 6;
  const int l = t & 63;
  const int l15 = l & 15;
  const int lg = l >> 4;
  const int c7 = l15 & 7;
  f32x4 acc[4];
#pragma unroll
  for (int ct = 0; ct < 4; ++ct) acc[ct] = f32x4{0.f, 0.f, 0.f, 0.f};
  const int arow = t >> 2;           // 0..63
  const int aseg = (t & 3) * 16;     // shorts
  const int sdst0 = arow * 64 + ((2 * (t & 3)) ^ (arow & 7)) * 8;
  const int afrag = (lg ^ c7) * 8;   // swizzled slot base (shorts)
  const int ard = (w * 16 + l15) * 64 + afrag;
  const unsigned short* gab = A + (size_t)(rowBase + arow) * 512 + aseg;
  const unsigned short* gwb = WT + (size_t)(colBase + arow) * 512 + aseg;
  bf16x8 ar0 = *reinterpret_cast<const bf16x8*>(gab);
  bf16x8 ar1 = *reinterpret_cast<const bf16x8*>(gab + 8);
  bf16x8 wr0 = *reinterpret_cast<const bf16x8*>(gwb);
  bf16x8 wr1 = *reinterpret_cast<const bf16x8*>(gwb + 8);
  for (int kb = 0; kb < 512; kb += 64) {
    *reinterpret_cast<bf16x8*>(&As[sdst0])     = ar0;
    *reinterpret_cast<bf16x8*>(&As[sdst0 ^ 8]) = ar1;
    *reinterpret_cast<bf16x8*>(&Ws[sdst0])     = wr0;
    *reinterpret_cast<bf16x8*>(&Ws[sdst0 ^ 8]) = wr1;
    __syncthreads();
    if (kb + 64 < 512) {
      ar0 = *reinterpret_cast<const bf16x8*>(gab + kb + 64);
      ar1 = *reinterpret_cast<const bf16x8*>(gab + kb + 72);
      wr0 = *reinterpret_cast<const bf16x8*>(gwb + kb + 64);
      wr1 = *reinterpret_cast<const bf16x8*>(gwb + kb + 72);
    }
#pragma unroll
    for (int ks = 0; ks < 2; ++ks) {
      bf16x8 af = *reinterpret_cast<const bf16x8*>(&As[ard ^ (ks ? 32 : 0)]);
#pragma unroll
      for (int ct = 0; ct < 4; ++ct) {
        bf16x8 bfr = *reinterpret_cast<const bf16x8*>(
            &Ws[(ct * 16 + l15) * 64 + (afrag ^ (ks ? 32 : 0))]);
        acc[ct] = __builtin_amdgcn_mfma_f32_16x16x32_bf16(af, bfr, acc[ct], 0, 0, 0);
      }
    }
    __syncthreads();
  }
#pragma unroll
  for (int ct = 0; ct < 4; ++ct)
#pragma unroll
    for (int r = 0; r < 4; ++r)
      Cs[w * 16 + lg * 4 + r][ct * 16 + l15] = acc[ct][r];
  __syncthreads();
}

// ---------------- K2: q projection + rotary + scale*log2e -> Q(b,h,q,d) bf16 ----------------
__global__ __launch_bounds__(256) void proj_q(
    const unsigned short* __restrict__ xq_bf, const unsigned short* __restrict__ WqT,
    const float* __restrict__ rotq, unsigned short* __restrict__ Qb) {
  __shared__ unsigned short As[64 * 64];
  __shared__ unsigned short Ws[64 * 64];
  __shared__ float Cs[64][66];
  int o = blockIdx.x;
  int swz = ((o & 7) << 7) + (o >> 3);
  int bn = swz & 7, bm = swz >> 3;     // bn == head, bm 0..127
  gemm_mainloop(xq_bf, WqT, As, Ws, Cs, bm * 64, bn * 64);
  int t = threadIdx.x;
#pragma unroll
  for (int i = 0; i < 8; ++i) {
    int p = i * 256 + t;
    int row = p >> 5, pc = p & 31, d0 = pc * 2;
    int grow = bm * 64 + row;           // b*NQ + q
    float c0 = Cs[row][d0], c1 = Cs[row][d0 + 1];
    const float* f = rotq + (size_t)grow * DH + d0;
    float f0 = f[0], f1 = f[1], s0, s1, co0, co1;
    __sincosf(f0, &s0, &co0);
    __sincosf(f1, &s1, &co1);
    float o0 = (c0 * co0 - c1 * s0) * SCALE_LOG2E;
    float o1 = (c1 * co1 + c0 * s1) * SCALE_LOG2E;
    ushort2 ov; ov.x = f2bf(o0); ov.y = f2bf(o1);
    int b = grow >> 10, qq = grow & 1023;
    *reinterpret_cast<ushort2*>(Qb + (((size_t)(b * H + bn) * NQ + qq) * DH + d0)) = ov;
  }
}

// ---------------- K3: kv projection + rotary -> K plain, V as attn-ready sigma image ----------------
__global__ __launch_bounds__(256) void proj_kv(
    const unsigned short* __restrict__ xc_bf, const unsigned short* __restrict__ WkvT,
    const float* __restrict__ rotc, unsigned short* __restrict__ Kb,
    unsigned short* __restrict__ VTb) {
  __shared__ unsigned short As[64 * 64];
  __shared__ unsigned short Ws[64 * 64];
  __shared__ float Cs[64][66];
  int o = blockIdx.x;
  int swz = ((o & 7) << 9) + (o >> 3);
  int bn = swz & 15, bm = swz >> 4;   // bn: 0..7 K-half, 8..15 V-half; bm 0..255
  gemm_mainloop(xc_bf, WkvT, As, Ws, Cs, bm * 64, bn * 64);
  int t = threadIdx.x;
  int h = bn & 7;
  int b = bm >> 5, chunk = bm & 31;
  if (bn < 8) {
#pragma unroll
    for (int i = 0; i < 8; ++i) {
      int p = i * 256 + t;
      int row = p >> 5, pc = p & 31, d0 = pc * 2;
      int grow = bm * 64 + row;           // b*NKV + kv
      float c0 = Cs[row][d0], c1 = Cs[row][d0 + 1];
      const float* f = rotc + (size_t)grow * DH + d0;
      float f0 = f[0], f1 = f[1], s0, s1, co0, co1;
      __sincosf(f0, &s0, &co0);
      __sincosf(f1, &s1, &co1);
      float o0 = c0 * co0 - c1 * s0;
      float o1 = c1 * co1 + c0 * s1;
      int kk = grow & 2047;
      ushort2 ov; ov.x = f2bf(o0); ov.y = f2bf(o1);
      *reinterpret_cast<ushort2*>(Kb + (((size_t)(b * H + h) * NKV + kk) * DH + d0)) = ov;
    }
  } else {
    unsigned short* vbase = VTb + (((size_t)(b * H + h) * 32 + chunk) * 64) * 64;
    int oc = t & 7;          // position octet
    int dd0 = t >> 3;        // 0..31
#pragma unroll
    for (int half = 0; half < 2; ++half) {
      int d = dd0 + half * 32;
      u32x4 pack;
#pragma unroll
      for (int j2 = 0; j2 < 4; ++j2) {
        unsigned int lohi[2];
#pragma unroll
        for (int e = 0; e < 2; ++e) {
          int p = oc * 8 + j2 * 2 + e;
          int pp = p & 31;
          int kv = (p >> 5) * 32 + ((pp & 1) ? ((pp >> 1) + 16) : (pp >> 1));
          float c0 = Cs[kv][d], cx = Cs[kv][d ^ 1];
          float f = rotc[(size_t)(bm * 64 + kv) * DH + d];
          float sn, cs;
          __sincosf(f, &sn, &cs);
          float val = (d & 1) ? (c0 * cs + cx * sn) : (c0 * cs - cx * sn);
          lohi[e] = f2bf(val);
        }
        pack[j2] = lohi[0] | (lohi[1] << 16);
      }
      *reinterpret_cast<u32x4*>(vbase + d * 64 + oc * 8) = pack;
    }
  }
}

// ---------------- K4: flash attention -> hi/lo bf16 split output ----------------
// T14 async-STAGE: K/V tile ic+1 is loaded to registers right after the
// post-stage barrier, so the global latency hides under QK^T+softmax+PV of
// tile ic. LDS stays single-buffered (32 KB -> residency unchanged).
__global__ __launch_bounds__(256) void attn_kernel(
    const unsigned short* __restrict__ Qb, const unsigned short* __restrict__ Kb,
    const unsigned short* __restrict__ VTb, const int* __restrict__ mask,
    const float* __restrict__ rotq,
    unsigned short* __restrict__ Ahb, unsigned short* __restrict__ Alb) {
  __shared__ unsigned short Ks[64 * 64];
  __shared__ unsigned short Vs[64 * 64];
  __shared__ unsigned short Ps[4 * 16 * 64];
  __shared__ float Ms[NKV];
  int ob = blockIdx.x;
  int swz = ((ob & 7) << 7) + (ob >> 3);
  int qb = swz & 15;
  int bh = swz >> 4;
  int b = bh >> 3, hh = bh & 7;
  int t = threadIdx.x, w = t >> 6, l = t & 63;
  int l15 = l & 15, lg = l >> 4;
  int c7 = l15 & 7;

  {
    const int* mrow = mask + b * NKV;
    int4 m0 = *reinterpret_cast<const int4*>(mrow + t * 8);
    int4 m1 = *reinterpret_cast<const int4*>(mrow + t * 8 + 4);
    Ms[t * 8 + 0] = m0.x ? 1.f : 0.f;
    Ms[t * 8 + 1] = m0.y ? 1.f : 0.f;
    Ms[t * 8 + 2] = m0.z ? 1.f : 0.f;
    Ms[t * 8 + 3] = m0.w ? 1.f : 0.f;
    Ms[t * 8 + 4] = m1.x ? 1.f : 0.f;
    Ms[t * 8 + 5] = m1.y ? 1.f : 0.f;
    Ms[t * 8 + 6] = m1.z ? 1.f : 0.f;
    Ms[t * 8 + 7] = m1.w ? 1.f : 0.f;
  }

  const unsigned short* qrow = Qb + ((size_t)bh * NQ + qb * 64 + w * 16 + l15) * DH;
  bf16x8 qa0 = *reinterpret_cast<const bf16x8*>(qrow + lg * 8);
  bf16x8 qa1 = *reinterpret_cast<const bf16x8*>(qrow + 32 + lg * 8);

  float plsum[4] = {0.f, 0.f, 0.f, 0.f};
  f32x4 acc[4];
#pragma unroll
  for (int ct = 0; ct < 4; ++ct) acc[ct] = f32x4{0.f, 0.f, 0.f, 0.f};

  const int srow = t >> 2;
  const int sseg = (t & 3) * 16;
  const int sdst0 = srow * 64 + ((2 * (t & 3)) ^ (srow & 7)) * 8;
  const int frag = (lg ^ c7) * 8;
  const int kbase = l15 * 64 + frag;
  const int prbase = w * 1024 + l15 * 64 + frag;
  unsigned int* pw = reinterpret_cast<unsigned int*>(Ps);
  const int lg4 = lg * 4, l3 = l15 & 3, sD = l15 >> 2;

  const unsigned short* gk = Kb + ((size_t)bh * NKV + srow) * DH + sseg;
  const unsigned short* gv = VTb + (((size_t)bh * 32) * 64 + srow) * 64 + sseg;

  // prologue: prefetch tile 0 into registers
  bf16x8 kr0 = *reinterpret_cast<const bf16x8*>(gk);
  bf16x8 kr1 = *reinterpret_cast<const bf16x8*>(gk + 8);
  bf16x8 vr0 = *reinterpret_cast<const bf16x8*>(gv);
  bf16x8 vr1 = *reinterpret_cast<const bf16x8*>(gv + 8);
  gk += 4096; gv += 4096;

  for (int ic = 0; ic < NKV / 64; ++ic) {
    // write the prefetched tile to LDS (compiler inserts the vmcnt wait here)
    *reinterpret_cast<bf16x8*>(&Ks[sdst0])     = kr0;
    *reinterpret_cast<bf16x8*>(&Ks[sdst0 ^ 8]) = kr1;
    *reinterpret_cast<bf16x8*>(&Vs[sdst0])     = vr0;
    *reinterpret_cast<bf16x8*>(&Vs[sdst0 ^ 8]) = vr1;
    __syncthreads();
    // issue next tile's global loads — they stay in flight across the compute
    if (ic + 1 < NKV / 64) {
      kr0 = *reinterpret_cast<const bf16x8*>(gk);
      kr1 = *reinterpret_cast<const bf16x8*>(gk + 8);
      vr0 = *reinterpret_cast<const bf16x8*>(gv);
      vr1 = *reinterpret_cast<const bf16x8*>(gv + 8);
      gk += 4096; gv += 4096;
    }
    f32x4 s[4];
    __builtin_amdgcn_s_setprio(1);
#pragma unroll
    for (int tt = 0; tt < 4; ++tt) {
      f32x4 z = f32x4{0.f, 0.f, 0.f, 0.f};
      bf16x8 k0 = *reinterpret_cast<const bf16x8*>(&Ks[tt * 1024 + kbase]);
      z = __builtin_amdgcn_mfma_f32_16x16x32_bf16(qa0, k0, z, 0, 0, 0);
      bf16x8 k1 = *reinterpret_cast<const bf16x8*>(&Ks[tt * 1024 + (kbase ^ 32)]);
      z = __builtin_amdgcn_mfma_f32_16x16x32_bf16(qa1, k1, z, 0, 0, 0);
      s[tt] = z;
    }
    __builtin_amdgcn_s_setprio(0);
    float mv[4];
#pragma unroll
    for (int tt = 0; tt < 4; ++tt) mv[tt] = Ms[ic * 64 + tt * 16 + l15];
    float p[4][4];
#pragma unroll
    for (int tt = 0; tt < 4; ++tt)
#pragma unroll
      for (int r = 0; r < 4; ++r) {
        float e;
        asm("v_exp_f32 %0, %1" : "=v"(e) : "v"(s[tt][r]));
        p[tt][r] = e * mv[tt];
      }
#pragma unroll
    for (int r = 0; r < 4; ++r)
      plsum[r] += (p[0][r] + p[1][r]) + (p[2][r] + p[3][r]);
#pragma unroll
    for (int r = 0; r < 4; ++r) {
      unsigned int d01, d23;
      asm("v_cvt_pk_bf16_f32 %0, %1, %2" : "=v"(d01) : "v"(p[0][r]), "v"(p[1][r]));
      asm("v_cvt_pk_bf16_f32 %0, %1, %2" : "=v"(d23) : "v"(p[2][r]), "v"(p[3][r]));
      int row = lg4 + r;
      int rb = row & 7;
      int dwl = ((sD ^ rb) << 2) + l3;
      int pb = w * 512 + row * 32 + dwl;
      pw[pb] = d01;
      pw[pb ^ 16] = d23;
    }
    asm volatile("s_waitcnt lgkmcnt(0)" ::: "memory");
    __builtin_amdgcn_sched_barrier(0);
    __builtin_amdgcn_s_setprio(1);
#pragma unroll
    for (int ks = 0; ks < 2; ++ks) {
      bf16x8 pa = *reinterpret_cast<const bf16x8*>(&Ps[(prbase ^ (ks ? 32 : 0))]);
#pragma unroll
      for (int ct = 0; ct < 4; ++ct) {
        bf16x8 vb = *reinterpret_cast<const bf16x8*>(
            &Vs[ct * 1024 + (kbase ^ (ks ? 32 : 0))]);
        acc[ct] = __builtin_amdgcn_mfma_f32_16x16x32_bf16(pa, vb, acc[ct], 0, 0, 0);
      }
    }
    __builtin_amdgcn_s_setprio(0);
    __syncthreads();
  }
#pragma unroll
  for (int d = 1; d < 16; d <<= 1)
#pragma unroll
    for (int r = 0; r < 4; ++r) plsum[r] += __shfl_xor(plsum[r], d);
  float inv[4];
#pragma unroll
  for (int r = 0; r < 4; ++r) inv[r] = 1.0f / plsum[r];

  // epilogue: normalize + inverse rotary + hi/lo bf16 split store
  int q0 = qb * 64 + w * 16 + lg * 4;
#pragma unroll
  for (int r = 0; r < 4; ++r) {
    int grow = b * NQ + q0 + r;
    const float* frow = rotq + (size_t)grow * DH;
    size_t obase = (size_t)grow * INNER + hh * DH;
#pragma unroll
    for (int ct = 0; ct < 4; ++ct) {
      int d = ct * 16 + l15;
      float x = acc[ct][r] * inv[r];
      float nb = __shfl_xor(x, 1);
      float f = frow[d];
      float sn, cs;
      __sincosf(f, &sn, &cs);
      float ov = (d & 1) ? (x * cs - nb * sn) : (x * cs + nb * sn);
      unsigned short hb = f2bf(ov);
      Ahb[obase + d] = hb;
      Alb[obase + d] = f2bf(ov - bf2f(hb));
    }
  }
}

// ---------------- K5: final GEMM via bf16 hi/lo split (3-term), MFMA ----------------
// out = Ah*Wh + Al*Wh + Ah*Wl + bias   (Al*Wl dropped, ~2^-18 relative)
__global__ __launch_bounds__(256) void final_gemm(
    const unsigned short* __restrict__ Ah, const unsigned short* __restrict__ Al,
    const unsigned short* __restrict__ Wh, const unsigned short* __restrict__ Wl,
    const float* __restrict__ bo, float* __restrict__ out) {
  __shared__ unsigned short AhS[64 * 64];
  __shared__ unsigned short AlS[64 * 64];
  __shared__ unsigned short WhS[64 * 64];
  __shared__ unsigned short WlS[64 * 64];
  int o = blockIdx.x;
  int swz = ((o & 7) << 7) + (o >> 3);
  int bn = swz & 7, bm = swz >> 3;    // bm 0..127 (rows of 64), bn 0..7 (cols of 64)
  const int t = threadIdx.x;
  const int w = t >> 6, l = t & 63;
  const int l15 = l & 15, lg = l >> 4, c7 = l15 & 7;
  f32x4 acc[4];
#pragma unroll
  for (int ct = 0; ct < 4; ++ct) acc[ct] = f32x4{0.f, 0.f, 0.f, 0.f};
  const int arow = t >> 2;
  const int aseg = (t & 3) * 16;
  const int sdst0 = arow * 64 + ((2 * (t & 3)) ^ (arow & 7)) * 8;
  const int afrag = (lg ^ c7) * 8;
  const int ard = (w * 16 + l15) * 64 + afrag;
  const unsigned short* gah = Ah + (size_t)(bm * 64 + arow) * 512 + aseg;
  const unsigned short* gal = Al + (size_t)(bm * 64 + arow) * 512 + aseg;
  const unsigned short* gwh = Wh + (size_t)(bn * 64 + arow) * 512 + aseg;
  const unsigned short* gwl = Wl + (size_t)(bn * 64 + arow) * 512 + aseg;
  // prologue: prefetch K-step 0 into registers (T14)
  bf16x8 rah0 = *reinterpret_cast<const bf16x8*>(gah);
  bf16x8 rah1 = *reinterpret_cast<const bf16x8*>(gah + 8);
  bf16x8 ral0 = *reinterpret_cast<const bf16x8*>(gal);
  bf16x8 ral1 = *reinterpret_cast<const bf16x8*>(gal + 8);
  bf16x8 rwh0 = *reinterpret_cast<const bf16x8*>(gwh);
  bf16x8 rwh1 = *reinterpret_cast<const bf16x8*>(gwh + 8);
  bf16x8 rwl0 = *reinterpret_cast<const bf16x8*>(gwl);
  bf16x8 rwl1 = *reinterpret_cast<const bf16x8*>(gwl + 8);
  for (int kb = 0; kb < 512; kb += 64) {
    *reinterpret_cast<bf16x8*>(&AhS[sdst0])     = rah0;
    *reinterpret_cast<bf16x8*>(&AhS[sdst0 ^ 8]) = rah1;
    *reinterpret_cast<bf16x8*>(&AlS[sdst0])     = ral0;
    *reinterpret_cast<bf16x8*>(&AlS[sdst0 ^ 8]) = ral1;
    *reinterpret_cast<bf16x8*>(&WhS[sdst0])     = rwh0;
    *reinterpret_cast<bf16x8*>(&WhS[sdst0 ^ 8]) = rwh1;
    *reinterpret_cast<bf16x8*>(&WlS[sdst0])     = rwl0;
    *reinterpret_cast<bf16x8*>(&WlS[sdst0 ^ 8]) = rwl1;
    __syncthreads();
    if (kb + 64 < 512) {
      rah0 = *reinterpret_cast<const bf16x8*>(gah + kb + 64);
      rah1 = *reinterpret_cast<const bf16x8*>(gah + kb + 72);
      ral0 = *reinterpret_cast<const bf16x8*>(gal + kb + 64);
      ral1 = *reinterpret_cast<const bf16x8*>(gal + kb + 72);
      rwh0 = *reinterpret_cast<const bf16x8*>(gwh + kb + 64);
      rwh1 = *reinterpret_cast<const bf16x8*>(gwh + kb + 72);
      rwl0 = *reinterpret_cast<const bf16x8*>(gwl + kb + 64);
      rwl1 = *reinterpret_cast<const bf16x8*>(gwl + kb + 72);
    }
#pragma unroll
    for (int ks = 0; ks < 2; ++ks) {
      const int x = ks ? 32 : 0;
      bf16x8 ah = *reinterpret_cast<const bf16x8*>(&AhS[ard ^ x]);
      bf16x8 al = *reinterpret_cast<const bf16x8*>(&AlS[ard ^ x]);
#pragma unroll
      for (int ct = 0; ct < 4; ++ct) {
        const int wb = (ct * 16 + l15) * 64 + (afrag ^ x);
        bf16x8 wh = *reinterpret_cast<const bf16x8*>(&WhS[wb]);
        bf16x8 wl = *reinterpret_cast<const bf16x8*>(&WlS[wb]);
        acc[ct] = __builtin_amdgcn_mfma_f32_16x16x32_bf16(ah, wh, acc[ct], 0, 0, 0);
        acc[ct] = __builtin_amdgcn_mfma_f32_16x16x32_bf16(al, wh, acc[ct], 0, 0, 0);
        acc[ct] = __builtin_amdgcn_mfma_f32_16x16x32_bf16(ah, wl, acc[ct], 0, 0, 0);
      }
    }
    __syncthreads();
  }
  int row0 = bm * 64 + w * 16 + lg * 4;
#pragma unroll
  for (int ct = 0; ct < 4; ++ct) {
    int col = bn * 64 + ct * 16 + l15;
    float bv = bo[col];
#pragma unroll
    for (int r = 0; r < 4; ++r)
      out[(size_t)(row0 + r) * 512 + col] = acc[ct][r] + bv;
  }
}

extern "C" void kernel_launch(void* const* d_in, const int* in_sizes, int n_in,
                              void* d_out, int out_size, void* d_ws, size_t ws_size,
                              hipStream_t stream) {
  const float* x_query   = (const float*)d_in[0];
  const float* x_context = (const float*)d_in[1];
  const float* rot_q     = (const float*)d_in[2];
  const float* rot_c     = (const float*)d_in[3];
  const int*   cmask     = (const int*)d_in[4];
  const float* ln_q_g    = (const float*)d_in[5];
  const float* ln_q_b    = (const float*)d_in[6];
  const float* ln_c_g    = (const float*)d_in[7];
  const float* ln_c_b    = (const float*)d_in[8];
  const float* Wq        = (const float*)d_in[9];
  const float* Wkv       = (const float*)d_in[10];
  const float* Wo        = (const float*)d_in[11];
  const float* bo        = (const float*)d_in[12];
  float* out = (float*)d_out;

  char* ws = (char*)d_ws;
  unsigned short* xq_bf = (unsigned short*)(ws + 0);          // 8 MB
  unsigned short* xc_bf = (unsigned short*)(ws + 8388608);    // 16 MB
  unsigned short* Ahb   = (unsigned short*)(ws + 0);          // 8 MB (after projections)
  unsigned short* Alb   = (unsigned short*)(ws + 8388608);    // 8 MB (after proj_kv)
  unsigned short* WqT   = (unsigned short*)(ws + 25165824);   // 0.5 MB
  unsigned short* WkvT  = (unsigned short*)(ws + 25690112);   // 1 MB
  unsigned short* Qb    = (unsigned short*)(ws + 26738688);   // 8 MB
  unsigned short* Kb    = (unsigned short*)(ws + 35127296);   // 16 MB
  unsigned short* VTb   = (unsigned short*)(ws + 51904512);   // 16 MB
  unsigned short* WohT  = (unsigned short*)(ws + 68681728);   // 0.5 MB
  unsigned short* WolT  = (unsigned short*)(ws + 69206016);   // 0.5 MB

  prep_weights<<<dim3(256), dim3(256), 0, stream>>>(Wq, Wkv, Wo, WqT, WkvT, WohT, WolT);
  ln_kernel<<<dim3(24576), dim3(256), 0, stream>>>(x_query, x_context, ln_q_g, ln_q_b,
                                                   ln_c_g, ln_c_b, xq_bf, xc_bf);
  proj_q<<<dim3(1024), dim3(256), 0, stream>>>(xq_bf, WqT, rot_q, Qb);
  proj_kv<<<dim3(4096), dim3(256), 0, stream>>>(xc_bf, WkvT, rot_c, Kb, VTb);
  attn_kernel<<<dim3(1024), dim3(256), 0, stream>>>(Qb, Kb, VTb, cmask, rot_q, Ahb, Alb);
  final_gemm<<<dim3(1024), dim3(256), 0, stream>>>(Ahb, Alb, WohT, WolT, bo, out);
}

// Round 2
// 154.724 us; speedup vs baseline: 1.0484x; 1.0041x over previous
//
#include <hip/hip_runtime.h>
#include <hip/hip_bf16.h>
#include <math.h>

#define BB 8
#define NQ 1024
#define NKV 2048
#define DIM 512
#define H 8
#define DH 64
#define INNER 512
// 0.125 * log2(e): folded into Q so QK^T scores feed v_exp_f32 (2^x) directly
#define SCALE_LOG2E 0.18033688011112042f

typedef __bf16 bf16x8 __attribute__((ext_vector_type(8)));
typedef float f32x4 __attribute__((ext_vector_type(4)));
typedef unsigned int u32x4 __attribute__((ext_vector_type(4)));

__device__ __forceinline__ unsigned short f2bf(float f) {
  union { float f; unsigned int u; } v; v.f = f;
  unsigned int r = v.u + 0x7fffu + ((v.u >> 16) & 1u);
  return (unsigned short)(r >> 16);
}
__device__ __forceinline__ float bf2f(unsigned short h) {
  union { unsigned int u; float f; } v; v.u = ((unsigned int)h) << 16;
  return v.f;
}

// ---------------- K0: cast/transpose weights to bf16; Wo also hi/lo split ----------------
__global__ __launch_bounds__(256) void prep_weights(
    const float* __restrict__ Wq, const float* __restrict__ Wkv,
    const float* __restrict__ Wo,
    unsigned short* __restrict__ WqT, unsigned short* __restrict__ WkvT,
    unsigned short* __restrict__ WohT, unsigned short* __restrict__ WolT) {
  __shared__ float T[64][65];
  int blk = blockIdx.x;
  const float* src; int Wd, ti, tj, mode;
  unsigned short* dst = nullptr;
  if (blk < 64) { src = Wq;  dst = WqT;  Wd = 512;  ti = blk >> 3; tj = blk & 7; mode = 0; }
  else if (blk < 192) { int b2 = blk - 64; src = Wkv; dst = WkvT; Wd = 1024; ti = b2 >> 4; tj = b2 & 15; mode = 0; }
  else { int b2 = blk - 192; src = Wo; Wd = 512; ti = b2 >> 3; tj = b2 & 7; mode = 1; }
  int t = threadIdx.x;
#pragma unroll
  for (int i = 0; i < 16; ++i) {
    int idx = i * 256 + t;
    int r = idx >> 6, c = idx & 63;
    T[r][c] = src[(size_t)(ti * 64 + r) * Wd + tj * 64 + c];
  }
  __syncthreads();
#pragma unroll
  for (int i = 0; i < 16; ++i) {
    int idx = i * 256 + t;
    int n = idx >> 6, k = idx & 63;
    float v = T[k][n];
    size_t off = (size_t)(tj * 64 + n) * 512 + ti * 64 + k;
    if (mode == 0) {
      dst[off] = f2bf(v);
    } else {
      unsigned short hb = f2bf(v);
      WohT[off] = hb;
      WolT[off] = f2bf(v - bf2f(hb));
    }
  }
}

// ---------------- K1: LayerNorm -> bf16 ----------------
__global__ __launch_bounds__(256) void ln_kernel(
    const float* __restrict__ xq, const float* __restrict__ xc,
    const float* __restrict__ gq, const float* __restrict__ bq,
    const float* __restrict__ gc, const float* __restrict__ bc,
    unsigned short* __restrict__ xq_bf, unsigned short* __restrict__ xc_bf) {
  int row = blockIdx.x;
  const float* x; const float* g; const float* bb; unsigned short* out;
  if (row < BB * NQ) {
    x = xq + (size_t)row * DIM; g = gq; bb = bq; out = xq_bf + (size_t)row * DIM;
  } else {
    int r = row - BB * NQ;
    x = xc + (size_t)r * DIM; g = gc; bb = bc; out = xc_bf + (size_t)r * DIM;
  }
  int t = threadIdx.x;
  float2 v = *reinterpret_cast<const float2*>(x + t * 2);
  float s = v.x + v.y;
  float ss = v.x * v.x + v.y * v.y;
#pragma unroll
  for (int d = 1; d < 64; d <<= 1) { s += __shfl_xor(s, d); ss += __shfl_xor(ss, d); }
  __shared__ float red[8];
  int wid = t >> 6, lane = t & 63;
  if (lane == 0) { red[wid] = s; red[4 + wid] = ss; }
  __syncthreads();
  s = red[0] + red[1] + red[2] + red[3];
  ss = red[4] + red[5] + red[6] + red[7];
  float mu = s * (1.0f / DIM);
  float var = ss * (1.0f / DIM) - mu * mu;
  float rs = rsqrtf(var + 1e-5f);
  float y0 = (v.x - mu) * rs * g[t * 2] + bb[t * 2];
  float y1 = (v.y - mu) * rs * g[t * 2 + 1] + bb[t * 2 + 1];
  ushort2 o; o.x = f2bf(y0); o.y = f2bf(y1);
  *reinterpret_cast<ushort2*>(out + t * 2) = o;
}

// ---------------- shared MFMA GEMM mainloop: 64x64 C tile, K=512, XOR-swizzled LDS ----------------
// T14 async-STAGE: next K-step's global loads issued right after the post-stage
// barrier so HBM/L2 latency hides under the MFMA phase.
__device__ __forceinline__ void gemm_mainloop(
    const unsigned short* __restrict__ A, const unsigned short* __restrict__ WT,
    unsigned short* As, unsigned short* Ws, float (*Cs)[66],
    int rowBase, int colBase) {
  const int t = threadIdx.x;
  const int w = t >> 6;
  const int l = t & 63;
  const int l15 = l & 15;
  const int lg = l >> 4;
  const int c7 = l15 & 7;
  f32x4 acc[4];
#pragma unroll
  for (int ct = 0; ct < 4; ++ct) acc[ct] = f32x4{0.f, 0.f, 0.f, 0.f};
  const int arow = t >> 2;           // 0..63
  const int aseg = (t & 3) * 16;     // shorts
  const int sdst0 = arow * 64 + ((2 * (t & 3)) ^ (arow & 7)) * 8;
  const int afrag = (lg ^ c7) * 8;   // swizzled slot base (shorts)
  const int ard = (w * 16 + l15) * 64 + afrag;
  const unsigned short* gab = A + (size_t)(rowBase + arow) * 512 + aseg;
  const unsigned short* gwb = WT + (size_t)(colBase + arow) * 512 + aseg;
  bf16x8 ar0 = *reinterpret_cast<const bf16x8*>(gab);
  bf16x8 ar1 = *reinterpret_cast<const bf16x8*>(gab + 8);
  bf16x8 wr0 = *reinterpret_cast<const bf16x8*>(gwb);
  bf16x8 wr1 = *reinterpret_cast<const bf16x8*>(gwb + 8);
  for (int kb = 0; kb < 512; kb += 64) {
    *reinterpret_cast<bf16x8*>(&As[sdst0])     = ar0;
    *reinterpret_cast<bf16x8*>(&As[sdst0 ^ 8]) = ar1;
    *reinterpret_cast<bf16x8*>(&Ws[sdst0])     = wr0;
    *reinterpret_cast<bf16x8*>(&Ws[sdst0 ^ 8]) = wr1;
    __syncthreads();
    if (kb + 64 < 512) {
      ar0 = *reinterpret_cast<const bf16x8*>(gab + kb + 64);
      ar1 = *reinterpret_cast<const bf16x8*>(gab + kb + 72);
      wr0 = *reinterpret_cast<const bf16x8*>(gwb + kb + 64);
      wr1 = *reinterpret_cast<const bf16x8*>(gwb + kb + 72);
    }
#pragma unroll
    for (int ks = 0; ks < 2; ++ks) {
      bf16x8 af = *reinterpret_cast<const bf16x8*>(&As[ard ^ (ks ? 32 : 0)]);
#pragma unroll
      for (int ct = 0; ct < 4; ++ct) {
        bf16x8 bfr = *reinterpret_cast<const bf16x8*>(
            &Ws[(ct * 16 + l15) * 64 + (afrag ^ (ks ? 32 : 0))]);
        acc[ct] = __builtin_amdgcn_mfma_f32_16x16x32_bf16(af, bfr, acc[ct], 0, 0, 0);
      }
    }
    __syncthreads();
  }
#pragma unroll
  for (int ct = 0; ct < 4; ++ct)
#pragma unroll
    for (int r = 0; r < 4; ++r)
      Cs[w * 16 + lg * 4 + r][ct * 16 + l15] = acc[ct][r];
  __syncthreads();
}

// ---------------- K2: q projection + rotary + scale*log2e -> Q(b,h,q,d) bf16 ----------------
__global__ __launch_bounds__(256) void proj_q(
    const unsigned short* __restrict__ xq_bf, const unsigned short* __restrict__ WqT,
    const float* __restrict__ rotq, unsigned short* __restrict__ Qb) {
  __shared__ unsigned short As[64 * 64];
  __shared__ unsigned short Ws[64 * 64];
  __shared__ float Cs[64][66];
  int o = blockIdx.x;
  int swz = ((o & 7) << 7) + (o >> 3);
  int bn = swz & 7, bm = swz >> 3;     // bn == head, bm 0..127
  gemm_mainloop(xq_bf, WqT, As, Ws, Cs, bm * 64, bn * 64);
  int t = threadIdx.x;
#pragma unroll
  for (int i = 0; i < 8; ++i) {
    int p = i * 256 + t;
    int row = p >> 5, pc = p & 31, d0 = pc * 2;
    int grow = bm * 64 + row;           // b*NQ + q
    float c0 = Cs[row][d0], c1 = Cs[row][d0 + 1];
    const float* f = rotq + (size_t)grow * DH + d0;
    float f0 = f[0], f1 = f[1], s0, s1, co0, co1;
    __sincosf(f0, &s0, &co0);
    __sincosf(f1, &s1, &co1);
    float o0 = (c0 * co0 - c1 * s0) * SCALE_LOG2E;
    float o1 = (c1 * co1 + c0 * s1) * SCALE_LOG2E;
    ushort2 ov; ov.x = f2bf(o0); ov.y = f2bf(o1);
    int b = grow >> 10, qq = grow & 1023;
    *reinterpret_cast<ushort2*>(Qb + (((size_t)(b * H + bn) * NQ + qq) * DH + d0)) = ov;
  }
}

// ---------------- K3: kv projection + rotary -> K plain, V sigma image ----------------
// Mask folded in here: masked kv rows of K and V are zeroed. In attention a
// masked column then yields s=0 exactly -> p=2^0=1 exactly, and PV adds 1*0=0;
// the softmax denominator is corrected by subtracting n_masked in K4.
__global__ __launch_bounds__(256) void proj_kv(
    const unsigned short* __restrict__ xc_bf, const unsigned short* __restrict__ WkvT,
    const float* __restrict__ rotc, const int* __restrict__ cmask,
    unsigned short* __restrict__ Kb, unsigned short* __restrict__ VTb) {
  __shared__ unsigned short As[64 * 64];
  __shared__ unsigned short Ws[64 * 64];
  __shared__ float Cs[64][66];
  int o = blockIdx.x;
  int swz = ((o & 7) << 9) + (o >> 3);
  int bn = swz & 15, bm = swz >> 4;   // bn: 0..7 K-half, 8..15 V-half; bm 0..255
  gemm_mainloop(xc_bf, WkvT, As, Ws, Cs, bm * 64, bn * 64);
  int t = threadIdx.x;
  int h = bn & 7;
  int b = bm >> 5, chunk = bm & 31;
  if (bn < 8) {
#pragma unroll
    for (int i = 0; i < 8; ++i) {
      int p = i * 256 + t;
      int row = p >> 5, pc = p & 31, d0 = pc * 2;
      int grow = bm * 64 + row;           // b*NKV + kv
      float c0 = Cs[row][d0], c1 = Cs[row][d0 + 1];
      const float* f = rotc + (size_t)grow * DH + d0;
      float f0 = f[0], f1 = f[1], s0, s1, co0, co1;
      __sincosf(f0, &s0, &co0);
      __sincosf(f1, &s1, &co1);
      float mf = cmask[grow] ? 1.f : 0.f;
      float o0 = (c0 * co0 - c1 * s0) * mf;
      float o1 = (c1 * co1 + c0 * s1) * mf;
      int kk = grow & 2047;
      ushort2 ov; ov.x = f2bf(o0); ov.y = f2bf(o1);
      *reinterpret_cast<ushort2*>(Kb + (((size_t)(b * H + h) * NKV + kk) * DH + d0)) = ov;
    }
  } else {
    unsigned short* vbase = VTb + (((size_t)(b * H + h) * 32 + chunk) * 64) * 64;
    int oc = t & 7;          // position octet
    int dd0 = t >> 3;        // 0..31
#pragma unroll
    for (int half = 0; half < 2; ++half) {
      int d = dd0 + half * 32;
      u32x4 pack;
#pragma unroll
      for (int j2 = 0; j2 < 4; ++j2) {
        unsigned int lohi[2];
#pragma unroll
        for (int e = 0; e < 2; ++e) {
          int p = oc * 8 + j2 * 2 + e;
          int pp = p & 31;
          int kv = (p >> 5) * 32 + ((pp & 1) ? ((pp >> 1) + 16) : (pp >> 1));
          float c0 = Cs[kv][d], cx = Cs[kv][d ^ 1];
          float f = rotc[(size_t)(bm * 64 + kv) * DH + d];
          float sn, cs;
          __sincosf(f, &sn, &cs);
          float mf = cmask[bm * 64 + kv] ? 1.f : 0.f;
          float val = ((d & 1) ? (c0 * cs + cx * sn) : (c0 * cs - cx * sn)) * mf;
          lohi[e] = f2bf(val);
        }
        pack[j2] = lohi[0] | (lohi[1] << 16);
      }
      *reinterpret_cast<u32x4*>(vbase + d * 64 + oc * 8) = pack;
    }
  }
}

// ---------------- K4: flash attention -> hi/lo bf16 split output ----------------
// Double-buffered K/V staging: ONE barrier per KV tile (the post-PV barrier is
// unnecessary: a wave writing buf[cur^1] at iter ic+1 has passed barrier(ic),
// which requires all waves to have finished compute(ic-1), the last readers).
// Mask is pre-applied to K/V (proj_kv); denominator corrected by n_masked.
__global__ __launch_bounds__(256) void attn_kernel(
    const unsigned short* __restrict__ Qb, const unsigned short* __restrict__ Kb,
    const unsigned short* __restrict__ VTb, const int* __restrict__ mask,
    const float* __restrict__ rotq,
    unsigned short* __restrict__ Ahb, unsigned short* __restrict__ Alb) {
  __shared__ unsigned short Ks[2 * 64 * 64];
  __shared__ unsigned short Vs[2 * 64 * 64];
  __shared__ unsigned short Ps[4 * 16 * 64];
  int ob = blockIdx.x;
  int swz = ((ob & 7) << 7) + (ob >> 3);
  int qb = swz & 15;
  int bh = swz >> 4;
  int b = bh >> 3, hh = bh & 7;
  int t = threadIdx.x, w = t >> 6, l = t & 63;
  int l15 = l & 15, lg = l >> 4;
  int c7 = l15 & 7;

  // n_masked: each wave redundantly popcounts the 8KB mask row (L2-hot, once)
  float nmasked;
  {
    const int* mrow = mask + b * NKV;
    float msum = 0.f;
#pragma unroll
    for (int i = 0; i < 8; ++i) {
      int4 m = *reinterpret_cast<const int4*>(mrow + l * 4 + i * 256);
      msum += (m.x ? 1.f : 0.f) + (m.y ? 1.f : 0.f) +
              (m.z ? 1.f : 0.f) + (m.w ? 1.f : 0.f);
    }
#pragma unroll
    for (int d = 1; d < 64; d <<= 1) msum += __shfl_xor(msum, d);
    nmasked = (float)NKV - msum;
  }

  const unsigned short* qrow = Qb + ((size_t)bh * NQ + qb * 64 + w * 16 + l15) * DH;
  bf16x8 qa0 = *reinterpret_cast<const bf16x8*>(qrow + lg * 8);
  bf16x8 qa1 = *reinterpret_cast<const bf16x8*>(qrow + 32 + lg * 8);

  float plsum[4] = {0.f, 0.f, 0.f, 0.f};
  f32x4 acc[4];
#pragma unroll
  for (int ct = 0; ct < 4; ++ct) acc[ct] = f32x4{0.f, 0.f, 0.f, 0.f};

  const int srow = t >> 2;
  const int sseg = (t & 3) * 16;
  const int sdst0 = srow * 64 + ((2 * (t & 3)) ^ (srow & 7)) * 8;
  const int frag = (lg ^ c7) * 8;
  const int kbase = l15 * 64 + frag;
  const int prbase = w * 1024 + l15 * 64 + frag;
  unsigned int* pw = reinterpret_cast<unsigned int*>(Ps);
  const int lg4 = lg * 4, l3 = l15 & 3, sD = l15 >> 2;

  const unsigned short* gk = Kb + ((size_t)bh * NKV + srow) * DH + sseg;
  const unsigned short* gv = VTb + (((size_t)bh * 32) * 64 + srow) * 64 + sseg;

  // prologue: prefetch tile 0 into registers
  bf16x8 kr0 = *reinterpret_cast<const bf16x8*>(gk);
  bf16x8 kr1 = *reinterpret_cast<const bf16x8*>(gk + 8);
  bf16x8 vr0 = *reinterpret_cast<const bf16x8*>(gv);
  bf16x8 vr1 = *reinterpret_cast<const bf16x8*>(gv + 8);
  gk += 4096; gv += 4096;

#pragma unroll 2
  for (int ic = 0; ic < NKV / 64; ++ic) {
    const int bo_ = (ic & 1) << 12;   // double-buffer offset in shorts
    // write the prefetched tile to LDS (compiler inserts the vmcnt wait here)
    *reinterpret_cast<bf16x8*>(&Ks[bo_ + sdst0])       = kr0;
    *reinterpret_cast<bf16x8*>(&Ks[bo_ + (sdst0 ^ 8)]) = kr1;
    *reinterpret_cast<bf16x8*>(&Vs[bo_ + sdst0])       = vr0;
    *reinterpret_cast<bf16x8*>(&Vs[bo_ + (sdst0 ^ 8)]) = vr1;
    __syncthreads();
    // issue next tile's global loads — in flight across this tile's compute
    if (ic + 1 < NKV / 64) {
      kr0 = *reinterpret_cast<const bf16x8*>(gk);
      kr1 = *reinterpret_cast<const bf16x8*>(gk + 8);
      vr0 = *reinterpret_cast<const bf16x8*>(gv);
      vr1 = *reinterpret_cast<const bf16x8*>(gv + 8);
      gk += 4096; gv += 4096;
    }
    f32x4 s[4];
    __builtin_amdgcn_s_setprio(1);
#pragma unroll
    for (int tt = 0; tt < 4; ++tt) {
      f32x4 z = f32x4{0.f, 0.f, 0.f, 0.f};
      bf16x8 k0 = *reinterpret_cast<const bf16x8*>(&Ks[bo_ + tt * 1024 + kbase]);
      z = __builtin_amdgcn_mfma_f32_16x16x32_bf16(qa0, k0, z, 0, 0, 0);
      bf16x8 k1 = *reinterpret_cast<const bf16x8*>(&Ks[bo_ + tt * 1024 + (kbase ^ 32)]);
      z = __builtin_amdgcn_mfma_f32_16x16x32_bf16(qa1, k1, z, 0, 0, 0);
      s[tt] = z;
    }
    __builtin_amdgcn_s_setprio(0);
    float p[4][4];
#pragma unroll
    for (int tt = 0; tt < 4; ++tt)
#pragma unroll
      for (int r = 0; r < 4; ++r) {
        float e;
        asm("v_exp_f32 %0, %1" : "=v"(e) : "v"(s[tt][r]));
        p[tt][r] = e;
      }
#pragma unroll
    for (int r = 0; r < 4; ++r)
      plsum[r] += (p[0][r] + p[1][r]) + (p[2][r] + p[3][r]);
#pragma unroll
    for (int r = 0; r < 4; ++r) {
      unsigned int d01, d23;
      asm("v_cvt_pk_bf16_f32 %0, %1, %2" : "=v"(d01) : "v"(p[0][r]), "v"(p[1][r]));
      asm("v_cvt_pk_bf16_f32 %0, %1, %2" : "=v"(d23) : "v"(p[2][r]), "v"(p[3][r]));
      int row = lg4 + r;
      int rb = row & 7;
      int dwl = ((sD ^ rb) << 2) + l3;
      int pb = w * 512 + row * 32 + dwl;
      pw[pb] = d01;
      pw[pb ^ 16] = d23;
    }
    asm volatile("s_waitcnt lgkmcnt(0)" ::: "memory");
    __builtin_amdgcn_sched_barrier(0);
    __builtin_amdgcn_s_setprio(1);
#pragma unroll
    for (int ks = 0; ks < 2; ++ks) {
      bf16x8 pa = *reinterpret_cast<const bf16x8*>(&Ps[(prbase ^ (ks ? 32 : 0))]);
#pragma unroll
      for (int ct = 0; ct < 4; ++ct) {
        bf16x8 vb = *reinterpret_cast<const bf16x8*>(
            &Vs[bo_ + ct * 1024 + (kbase ^ (ks ? 32 : 0))]);
        acc[ct] = __builtin_amdgcn_mfma_f32_16x16x32_bf16(pa, vb, acc[ct], 0, 0, 0);
      }
    }
    __builtin_amdgcn_s_setprio(0);
    // no trailing barrier: next iter writes the other buffer
  }
#pragma unroll
  for (int d = 1; d < 16; d <<= 1)
#pragma unroll
    for (int r = 0; r < 4; ++r) plsum[r] += __shfl_xor(plsum[r], d);
  float inv[4];
#pragma unroll
  for (int r = 0; r < 4; ++r) inv[r] = 1.0f / (plsum[r] - nmasked);

  // epilogue: normalize + inverse rotary + hi/lo bf16 split store
  int q0 = qb * 64 + w * 16 + lg * 4;
#pragma unroll
  for (int r = 0; r < 4; ++r) {
    int grow = b * NQ + q0 + r;
    const float* frow = rotq + (size_t)grow * DH;
    size_t obase = (size_t)grow * INNER + hh * DH;
#pragma unroll
    for (int ct = 0; ct < 4; ++ct) {
      int d = ct * 16 + l15;
      float x = acc[ct][r] * inv[r];
      float nb = __shfl_xor(x, 1);
      float f = frow[d];
      float sn, cs;
      __sincosf(f, &sn, &cs);
      float ov = (d & 1) ? (x * cs - nb * sn) : (x * cs + nb * sn);
      unsigned short hb = f2bf(ov);
      Ahb[obase + d] = hb;
      Alb[obase + d] = f2bf(ov - bf2f(hb));
    }
  }
}

// ---------------- K5: final GEMM via bf16 hi/lo split (3-term), MFMA ----------------
// out = Ah*Wh + Al*Wh + Ah*Wl + bias   (Al*Wl dropped, ~2^-18 relative)
__global__ __launch_bounds__(256) void final_gemm(
    const unsigned short* __restrict__ Ah, const unsigned short* __restrict__ Al,
    const unsigned short* __restrict__ Wh, const unsigned short* __restrict__ Wl,
    const float* __restrict__ bo, float* __restrict__ out) {
  __shared__ unsigned short AhS[64 * 64];
  __shared__ unsigned short AlS[64 * 64];
  __shared__ unsigned short WhS[64 * 64];
  __shared__ unsigned short WlS[64 * 64];
  int o = blockIdx.x;
  int swz = ((o & 7) << 7) + (o >> 3);
  int bn = swz & 7, bm = swz >> 3;    // bm 0..127 (rows of 64), bn 0..7 (cols of 64)
  const int t = threadIdx.x;
  const int w = t >> 6, l = t & 63;
  const int l15 = l & 15, lg = l >> 4, c7 = l15 & 7;
  f32x4 acc[4];
#pragma unroll
  for (int ct = 0; ct < 4; ++ct) acc[ct] = f32x4{0.f, 0.f, 0.f, 0.f};
  const int arow = t >> 2;
  const int aseg = (t & 3) * 16;
  const int sdst0 = arow * 64 + ((2 * (t & 3)) ^ (arow & 7)) * 8;
  const int afrag = (lg ^ c7) * 8;
  const int ard = (w * 16 + l15) * 64 + afrag;
  const unsigned short* gah = Ah + (size_t)(bm * 64 + arow) * 512 + aseg;
  const unsigned short* gal = Al + (size_t)(bm * 64 + arow) * 512 + aseg;
  const unsigned short* gwh = Wh + (size_t)(bn * 64 + arow) * 512 + aseg;
  const unsigned short* gwl = Wl + (size_t)(bn * 64 + arow) * 512 + aseg;
  // prologue: prefetch K-step 0 into registers (T14)
  bf16x8 rah0 = *reinterpret_cast<const bf16x8*>(gah);
  bf16x8 rah1 = *reinterpret_cast<const bf16x8*>(gah + 8);
  bf16x8 ral0 = *reinterpret_cast<const bf16x8*>(gal);
  bf16x8 ral1 = *reinterpret_cast<const bf16x8*>(gal + 8);
  bf16x8 rwh0 = *reinterpret_cast<const bf16x8*>(gwh);
  bf16x8 rwh1 = *reinterpret_cast<const bf16x8*>(gwh + 8);
  bf16x8 rwl0 = *reinterpret_cast<const bf16x8*>(gwl);
  bf16x8 rwl1 = *reinterpret_cast<const bf16x8*>(gwl + 8);
  for (int kb = 0; kb < 512; kb += 64) {
    *reinterpret_cast<bf16x8*>(&AhS[sdst0])     = rah0;
    *reinterpret_cast<bf16x8*>(&AhS[sdst0 ^ 8]) = rah1;
    *reinterpret_cast<bf16x8*>(&AlS[sdst0])     = ral0;
    *reinterpret_cast<bf16x8*>(&AlS[sdst0 ^ 8]) = ral1;
    *reinterpret_cast<bf16x8*>(&WhS[sdst0])     = rwh0;
    *reinterpret_cast<bf16x8*>(&WhS[sdst0 ^ 8]) = rwh1;
    *reinterpret_cast<bf16x8*>(&WlS[sdst0])     = rwl0;
    *reinterpret_cast<bf16x8*>(&WlS[sdst0 ^ 8]) = rwl1;
    __syncthreads();
    if (kb + 64 < 512) {
      rah0 = *reinterpret_cast<const bf16x8*>(gah + kb + 64);
      rah1 = *reinterpret_cast<const bf16x8*>(gah + kb + 72);
      ral0 = *reinterpret_cast<const bf16x8*>(gal + kb + 64);
      ral1 = *reinterpret_cast<const bf16x8*>(gal + kb + 72);
      rwh0 = *reinterpret_cast<const bf16x8*>(gwh + kb + 64);
      rwh1 = *reinterpret_cast<const bf16x8*>(gwh + kb + 72);
      rwl0 = *reinterpret_cast<const bf16x8*>(gwl + kb + 64);
      rwl1 = *reinterpret_cast<const bf16x8*>(gwl + kb + 72);
    }
#pragma unroll
    for (int ks = 0; ks < 2; ++ks) {
      const int x = ks ? 32 : 0;
      bf16x8 ah = *reinterpret_cast<const bf16x8*>(&AhS[ard ^ x]);
      bf16x8 al = *reinterpret_cast<const bf16x8*>(&AlS[ard ^ x]);
#pragma unroll
      for (int ct = 0; ct < 4; ++ct) {
        const int wb = (ct * 16 + l15) * 64 + (afrag ^ x);
        bf16x8 wh = *reinterpret_cast<const bf16x8*>(&WhS[wb]);
        bf16x8 wl = *reinterpret_cast<const bf16x8*>(&WlS[wb]);
        acc[ct] = __builtin_amdgcn_mfma_f32_16x16x32_bf16(ah, wh, acc[ct], 0, 0, 0);
        acc[ct] = __builtin_amdgcn_mfma_f32_16x16x32_bf16(al, wh, acc[ct], 0, 0, 0);
        acc[ct] = __builtin_amdgcn_mfma_f32_16x16x32_bf16(ah, wl, acc[ct], 0, 0, 0);
      }
    }
    __syncthreads();
  }
  int row0 = bm * 64 + w * 16 + lg * 4;
#pragma unroll
  for (int ct = 0; ct < 4; ++ct) {
    int col = bn * 64 + ct * 16 + l15;
    float bv = bo[col];
#pragma unroll
    for (int r = 0; r < 4; ++r)
      out[(size_t)(row0 + r) * 512 + col] = acc[ct][r] + bv;
  }
}

extern "C" void kernel_launch(void* const* d_in, const int* in_sizes, int n_in,
                              void* d_out, int out_size, void* d_ws, size_t ws_size,
                              hipStream_t stream) {
  const float* x_query   = (const float*)d_in[0];
  const float* x_context = (const float*)d_in[1];
  const float* rot_q     = (const float*)d_in[2];
  const float* rot_c     = (const float*)d_in[3];
  const int*   cmask     = (const int*)d_in[4];
  const float* ln_q_g    = (const float*)d_in[5];
  const float* ln_q_b    = (const float*)d_in[6];
  const float* ln_c_g    = (const float*)d_in[7];
  const float* ln_c_b    = (const float*)d_in[8];
  const float* Wq        = (const float*)d_in[9];
  const float* Wkv       = (const float*)d_in[10];
  const float* Wo        = (const float*)d_in[11];
  const float* bo        = (const float*)d_in[12];
  float* out = (float*)d_out;

  char* ws = (char*)d_ws;
  unsigned short* xq_bf = (unsigned short*)(ws + 0);          // 8 MB
  unsigned short* xc_bf = (unsigned short*)(ws + 8388608);    // 16 MB
  unsigned short* Ahb   = (unsigned short*)(ws + 0);          // 8 MB (after projections)
  unsigned short* Alb   = (unsigned short*)(ws + 8388608);    // 8 MB (after proj_kv)
  unsigned short* WqT   = (unsigned short*)(ws + 25165824);   // 0.5 MB
  unsigned short* WkvT  = (unsigned short*)(ws + 25690112);   // 1 MB
  unsigned short* Qb    = (unsigned short*)(ws + 26738688);   // 8 MB
  unsigned short* Kb    = (unsigned short*)(ws + 35127296);   // 16 MB
  unsigned short* VTb   = (unsigned short*)(ws + 51904512);   // 16 MB
  unsigned short* WohT  = (unsigned short*)(ws + 68681728);   // 0.5 MB
  unsigned short* WolT  = (unsigned short*)(ws + 69206016);   // 0.5 MB

  prep_weights<<<dim3(256), dim3(256), 0, stream>>>(Wq, Wkv, Wo, WqT, WkvT, WohT, WolT);
  ln_kernel<<<dim3(24576), dim3(256), 0, stream>>>(x_query, x_context, ln_q_g, ln_q_b,
                                                   ln_c_g, ln_c_b, xq_bf, xc_bf);
  proj_q<<<dim3(1024), dim3(256), 0, stream>>>(xq_bf, WqT, rot_q, Qb);
  proj_kv<<<dim3(4096), dim3(256), 0, stream>>>(xc_bf, WkvT, rot_c, cmask, Kb, VTb);
  attn_kernel<<<dim3(1024), dim3(256), 0, stream>>>(Qb, Kb, VTb, cmask, rot_q, Ahb, Alb);
  final_gemm<<<dim3(1024), dim3(256), 0, stream>>>(Ahb, Alb, WohT, WolT, bo, out);
}